// Round 3
// baseline (632.442 us; speedup 1.0000x reference)
//
#include <hip/hip_runtime.h>

// Problem constants (from reference)
#define NBATCH 4096
#define NF     32
#define DIM    64
#define NPAIRS 496

// Tiling: one block = one (pair, 128-batch-row tile)
#define MTILE  128
#define LDAP   72    // LDS row stride in f16 elems: 64 + 8 pad (144 B, 16B-aligned, 2-way bank alias = free)

typedef _Float16 half8  __attribute__((ext_vector_type(8)));
typedef _Float16 half4v __attribute__((ext_vector_type(4)));
typedef float    floatx4 __attribute__((ext_vector_type(4)));

__global__ __launch_bounds__(256, 4)
void bilinear_mfma(const float* __restrict__ x, const float* __restrict__ W,
                   float* __restrict__ out) {
    // Only W needs LDS (4x reuse across waves). x_i rows are wave-private ->
    // loaded straight to registers (LDS staging gave zero reuse).
    __shared__ _Float16 sW[DIM * LDAP];     // 9216 B

    const int tid  = threadIdx.x;
    const int lane = tid & 63;
    const int wv   = tid >> 6;      // wave id 0..3
    const int lrow = lane & 15;
    const int quad = lane >> 4;

    const int p  = blockIdx.x % NPAIRS;   // pair-inner: consecutive blocks share x batch tile in L2
    const int bt = blockIdx.x / NPAIRS;
    const int b0 = bt * MTILE;

    // decode lexicographic combinations(range(32), 2): p -> (fi, fj)
    int fi = 0, rem = p;
    while (rem >= NF - 1 - fi) { rem -= NF - 1 - fi; ++fi; }
    const int fj = fi + 1 + rem;

    // ---- stage W[p] (64x64 fp32) -> sW (f16), float4 coalesced ----
    const float* Wp = W + (size_t)p * (DIM * DIM);
    #pragma unroll
    for (int it = 0; it < 4; ++it) {
        int idx = tid + 256 * it;          // float4 index 0..1023
        int o   = idx >> 4;                // 16 float4 per row
        int c4  = (idx & 15) << 2;
        const floatx4 v = *(const floatx4*)(Wp + o * DIM + c4);
        half4v hv;
        hv[0] = (_Float16)v[0]; hv[1] = (_Float16)v[1];
        hv[2] = (_Float16)v[2]; hv[3] = (_Float16)v[3];
        *(half4v*)(&sW[o * LDAP + c4]) = hv;   // 8B store, 8B-aligned
    }

    // ---- x_i fragments direct to registers (B-operand of swapped MFMA) ----
    // B[k][col=b] = x[b][k]; lane holds B[ks*32 + quad*8 + j][lrow]
    half8 bx[2][2];   // [bt2][ks]
    #pragma unroll
    for (int bt2 = 0; bt2 < 2; ++bt2) {
        const int b = b0 + wv * 32 + bt2 * 16 + lrow;
        const float* xrow = x + ((size_t)b * NF + fi) * DIM;
        #pragma unroll
        for (int ks = 0; ks < 2; ++ks) {
            const floatx4 v0 = *(const floatx4*)(xrow + ks * 32 + quad * 8);
            const floatx4 v1 = *(const floatx4*)(xrow + ks * 32 + quad * 8 + 4);
            half8 h;
            h[0] = (_Float16)v0[0]; h[1] = (_Float16)v0[1];
            h[2] = (_Float16)v0[2]; h[3] = (_Float16)v0[3];
            h[4] = (_Float16)v1[0]; h[5] = (_Float16)v1[1];
            h[6] = (_Float16)v1[2]; h[7] = (_Float16)v1[3];
            bx[bt2][ks] = h;
        }
    }
    __syncthreads();

    // ---- MFMA, operands SWAPPED: D[o][b] = A(W) * B(x) ----
    // A[row=o][k]: lane holds W[ot*16 + lrow][ks*32 + quad*8 + j]  (same read pattern as before)
    // D layout: col = lane&15 -> batch sub-row, row = quad*4 + r -> o (CONSECUTIVE d per lane!)
    floatx4 acc[2][4] = {};   // [bt2][ot]
    #pragma unroll
    for (int ks = 0; ks < 2; ++ks) {
        half8 aw[4];
        #pragma unroll
        for (int ot = 0; ot < 4; ++ot)
            aw[ot] = *(const half8*)(&sW[(ot * 16 + lrow) * LDAP + ks * 32 + quad * 8]);
        #pragma unroll
        for (int bt2 = 0; bt2 < 2; ++bt2)
            #pragma unroll
            for (int ot = 0; ot < 4; ++ot)
                acc[bt2][ot] = __builtin_amdgcn_mfma_f32_16x16x32_f16(aw[ot], bx[bt2][ks], acc[bt2][ot], 0, 0, 0);
    }

    // ---- epilogue: thread owns 4 consecutive d -> float4 xj load, float4 NT store ----
    #pragma unroll
    for (int bt2 = 0; bt2 < 2; ++bt2) {
        const size_t b = (size_t)(b0 + wv * 32 + bt2 * 16 + lrow);
        const float* xjrow = x + (b * NF + fj) * DIM;
        float* orow = out + b * (NPAIRS * DIM) + (size_t)p * DIM;
        #pragma unroll
        for (int ot = 0; ot < 4; ++ot) {
            const int o4 = ot * 16 + quad * 4;           // d offset of this thread's float4
            const floatx4 xj = *(const floatx4*)(xjrow + o4);
            const floatx4 a = acc[bt2][ot];
            floatx4 res;
            res[0] = a[0] * xj[0]; res[1] = a[1] * xj[1];
            res[2] = a[2] * xj[2]; res[3] = a[3] * xj[3];
            __builtin_nontemporal_store(res, (floatx4*)(orow + o4));
        }
    }
}

extern "C" void kernel_launch(void* const* d_in, const int* in_sizes, int n_in,
                              void* d_out, int out_size, void* d_ws, size_t ws_size,
                              hipStream_t stream) {
    const float* x = (const float*)d_in[0];   // (4096, 32, 64) fp32
    const float* W = (const float*)d_in[1];   // (496, 64, 64) fp32
    float* out = (float*)d_out;               // (4096, 496, 64) fp32

    dim3 grid(NPAIRS * (NBATCH / MTILE));     // 496 * 32 = 15872 blocks
    bilinear_mfma<<<grid, 256, 0, stream>>>(x, W, out);
}

// Round 4
// 611.875 us; speedup vs baseline: 1.0336x; 1.0336x over previous
//
#include <hip/hip_runtime.h>

// Problem constants (from reference)
#define NBATCH 4096
#define NF     32
#define DIM    64
#define NPAIRS 496
#define MTILE  128

#define X_ELEMS (NBATCH * NF * DIM)     // 8,388,608
#define W_ELEMS (NPAIRS * DIM * DIM)    // 2,031,616
#define X_V4    (X_ELEMS / 4)
#define TOT_V4  ((X_ELEMS + W_ELEMS) / 4)

typedef _Float16 half8  __attribute__((ext_vector_type(8)));
typedef _Float16 half4v __attribute__((ext_vector_type(4)));
typedef float    floatx4 __attribute__((ext_vector_type(4)));

// ---------------- pre-pass: fp32 -> f16 for x and W ----------------
__global__ __launch_bounds__(256)
void cvt_f16(const float* __restrict__ x, const float* __restrict__ W,
             _Float16* __restrict__ xh, _Float16* __restrict__ Wh) {
    int idx = blockIdx.x * 256 + threadIdx.x;
    const int stride = gridDim.x * 256;
    for (; idx < TOT_V4; idx += stride) {
        const float* src; _Float16* dst; int o;
        if (idx < X_V4) { src = x; dst = xh; o = idx * 4; }
        else            { src = W; dst = Wh; o = (idx - X_V4) * 4; }
        const floatx4 v = *(const floatx4*)(src + o);
        half4v h;
        h[0] = (_Float16)v[0]; h[1] = (_Float16)v[1];
        h[2] = (_Float16)v[2]; h[3] = (_Float16)v[3];
        *(half4v*)(dst + o) = h;
    }
}

// ---------------- main: all-f16 reads, LDS-free, barrier-free ----------------
// W_f16 totals 4 MB -> L2-resident per XCD by capacity alone; per-wave W fragment
// loads are 4x redundant across waves but hit L2 (cheap vs the fabric-rate reads
// that dominated the fp32 version).
__global__ __launch_bounds__(256, 4)
void bilinear_f16(const _Float16* __restrict__ xh, const _Float16* __restrict__ Wh,
                  float* __restrict__ out) {
    const int tid  = threadIdx.x;
    const int lane = tid & 63;
    const int wv   = tid >> 6;      // wave id 0..3 -> rows [wv*32, wv*32+32)
    const int lrow = lane & 15;
    const int quad = lane >> 4;

    const int p  = blockIdx.x % NPAIRS;   // pair-inner: contiguous block chunks share one x batch tile
    const int bt = blockIdx.x / NPAIRS;
    const int b0 = bt * MTILE;

    // decode lexicographic combinations(range(32), 2): p -> (fi, fj)
    int fi = 0, rem = p;
    while (rem >= NF - 1 - fi) { rem -= NF - 1 - fi; ++fi; }
    const int fj = fi + 1 + rem;

    // ---- A-operand: W[p] fragments straight from global (f16, L2-hot) ----
    // A[row=o][k]: lane holds W[ot*16 + lrow][ks*32 + quad*8 + j]
    const _Float16* Wp = Wh + (size_t)p * (DIM * DIM);
    half8 aw[2][4];   // [ks][ot]
    #pragma unroll
    for (int ks = 0; ks < 2; ++ks)
        #pragma unroll
        for (int ot = 0; ot < 4; ++ot)
            aw[ks][ot] = *(const half8*)(Wp + (ot * 16 + lrow) * DIM + ks * 32 + quad * 8);

    // ---- B-operand: x_i fragments direct to registers (f16) ----
    // B[k][col=b]: lane holds x[b0 + wv*32 + bt2*16 + lrow][fi][ks*32 + quad*8 + j]
    half8 bx[2][2];   // [bt2][ks]
    #pragma unroll
    for (int bt2 = 0; bt2 < 2; ++bt2) {
        const int b = b0 + wv * 32 + bt2 * 16 + lrow;
        const _Float16* xrow = xh + ((size_t)b * NF + fi) * DIM;
        #pragma unroll
        for (int ks = 0; ks < 2; ++ks)
            bx[bt2][ks] = *(const half8*)(xrow + ks * 32 + quad * 8);
    }

    // ---- MFMA (swapped): D[o][b] = A(W) * B(x_i) ----
    // D layout: col = lane&15 -> batch sub-row, row = quad*4 + r -> o (consecutive d per lane)
    floatx4 acc[2][4] = {};   // [bt2][ot]
    #pragma unroll
    for (int ks = 0; ks < 2; ++ks)
        #pragma unroll
        for (int bt2 = 0; bt2 < 2; ++bt2)
            #pragma unroll
            for (int ot = 0; ot < 4; ++ot)
                acc[bt2][ot] = __builtin_amdgcn_mfma_f32_16x16x32_f16(aw[ks][ot], bx[bt2][ks], acc[bt2][ot], 0, 0, 0);

    // ---- epilogue: xj (f16, cvt to fp32) multiply, float4 NT store ----
    #pragma unroll
    for (int bt2 = 0; bt2 < 2; ++bt2) {
        const size_t b = (size_t)(b0 + wv * 32 + bt2 * 16 + lrow);
        const _Float16* xjrow = xh + (b * NF + fj) * DIM;
        float* orow = out + b * (NPAIRS * DIM) + (size_t)p * DIM;
        #pragma unroll
        for (int ot = 0; ot < 4; ++ot) {
            const int o4 = ot * 16 + quad * 4;           // d offset of this thread's float4
            const half4v xj = *(const half4v*)(xjrow + o4);
            const floatx4 a = acc[bt2][ot];
            floatx4 res;
            res[0] = a[0] * (float)xj[0]; res[1] = a[1] * (float)xj[1];
            res[2] = a[2] * (float)xj[2]; res[3] = a[3] * (float)xj[3];
            __builtin_nontemporal_store(res, (floatx4*)(orow + o4));
        }
    }
}

// ---------------- fallback (ws too small): Round-3 kernel, fp32 reads ----------------
#define LDAP 72
__global__ __launch_bounds__(256, 4)
void bilinear_fb(const float* __restrict__ x, const float* __restrict__ W,
                 float* __restrict__ out) {
    __shared__ _Float16 sW[DIM * LDAP];
    const int tid = threadIdx.x, lane = tid & 63, wv = tid >> 6;
    const int lrow = lane & 15, quad = lane >> 4;
    const int p = blockIdx.x % NPAIRS, bt = blockIdx.x / NPAIRS, b0 = bt * MTILE;
    int fi = 0, rem = p;
    while (rem >= NF - 1 - fi) { rem -= NF - 1 - fi; ++fi; }
    const int fj = fi + 1 + rem;
    const float* Wp = W + (size_t)p * (DIM * DIM);
    #pragma unroll
    for (int it = 0; it < 4; ++it) {
        int idx = tid + 256 * it, o = idx >> 4, c4 = (idx & 15) << 2;
        const floatx4 v = *(const floatx4*)(Wp + o * DIM + c4);
        half4v hv; hv[0]=(_Float16)v[0]; hv[1]=(_Float16)v[1]; hv[2]=(_Float16)v[2]; hv[3]=(_Float16)v[3];
        *(half4v*)(&sW[o * LDAP + c4]) = hv;
    }
    half8 bx[2][2];
    #pragma unroll
    for (int bt2 = 0; bt2 < 2; ++bt2) {
        const int b = b0 + wv * 32 + bt2 * 16 + lrow;
        const float* xrow = x + ((size_t)b * NF + fi) * DIM;
        #pragma unroll
        for (int ks = 0; ks < 2; ++ks) {
            const floatx4 v0 = *(const floatx4*)(xrow + ks * 32 + quad * 8);
            const floatx4 v1 = *(const floatx4*)(xrow + ks * 32 + quad * 8 + 4);
            half8 h;
            h[0]=(_Float16)v0[0]; h[1]=(_Float16)v0[1]; h[2]=(_Float16)v0[2]; h[3]=(_Float16)v0[3];
            h[4]=(_Float16)v1[0]; h[5]=(_Float16)v1[1]; h[6]=(_Float16)v1[2]; h[7]=(_Float16)v1[3];
            bx[bt2][ks] = h;
        }
    }
    __syncthreads();
    floatx4 acc[2][4] = {};
    #pragma unroll
    for (int ks = 0; ks < 2; ++ks) {
        half8 aw[4];
        #pragma unroll
        for (int ot = 0; ot < 4; ++ot)
            aw[ot] = *(const half8*)(&sW[(ot * 16 + lrow) * LDAP + ks * 32 + quad * 8]);
        #pragma unroll
        for (int bt2 = 0; bt2 < 2; ++bt2)
            #pragma unroll
            for (int ot = 0; ot < 4; ++ot)
                acc[bt2][ot] = __builtin_amdgcn_mfma_f32_16x16x32_f16(aw[ot], bx[bt2][ks], acc[bt2][ot], 0, 0, 0);
    }
    #pragma unroll
    for (int bt2 = 0; bt2 < 2; ++bt2) {
        const size_t b = (size_t)(b0 + wv * 32 + bt2 * 16 + lrow);
        const float* xjrow = x + (b * NF + fj) * DIM;
        float* orow = out + b * (NPAIRS * DIM) + (size_t)p * DIM;
        #pragma unroll
        for (int ot = 0; ot < 4; ++ot) {
            const int o4 = ot * 16 + quad * 4;
            const floatx4 xj = *(const floatx4*)(xjrow + o4);
            const floatx4 a = acc[bt2][ot];
            floatx4 res;
            res[0]=a[0]*xj[0]; res[1]=a[1]*xj[1]; res[2]=a[2]*xj[2]; res[3]=a[3]*xj[3];
            __builtin_nontemporal_store(res, (floatx4*)(orow + o4));
        }
    }
}

extern "C" void kernel_launch(void* const* d_in, const int* in_sizes, int n_in,
                              void* d_out, int out_size, void* d_ws, size_t ws_size,
                              hipStream_t stream) {
    const float* x = (const float*)d_in[0];   // (4096, 32, 64) fp32
    const float* W = (const float*)d_in[1];   // (496, 64, 64) fp32
    float* out = (float*)d_out;               // (4096, 496, 64) fp32

    const size_t need = (size_t)(X_ELEMS + W_ELEMS) * sizeof(_Float16);  // 20.9 MB
    dim3 grid(NPAIRS * (NBATCH / MTILE));     // 15872 blocks

    if (ws_size >= need) {
        _Float16* xh = (_Float16*)d_ws;
        _Float16* Wh = xh + X_ELEMS;
        cvt_f16<<<dim3(2048), 256, 0, stream>>>(x, W, xh, Wh);
        bilinear_f16<<<grid, 256, 0, stream>>>(xh, Wh, out);
    } else {
        bilinear_fb<<<grid, 256, 0, stream>>>(x, W, out);
    }
}

// Round 5
// 563.429 us; speedup vs baseline: 1.1225x; 1.0860x over previous
//
#include <hip/hip_runtime.h>

// Problem constants (from reference)
#define NBATCH 4096
#define NF     32
#define DIM    64
#define NPAIRS 496
#define MTILE  128

#define X_ELEMS (NBATCH * NF * DIM)     // 8,388,608
#define W_ELEMS (NPAIRS * DIM * DIM)    // 2,031,616
#define X_V4    (X_ELEMS / 4)
#define TOT_V4  ((X_ELEMS + W_ELEMS) / 4)

#define LDSF 68   // f32 LDS row stride: 64 + 4 pad

typedef _Float16 half8  __attribute__((ext_vector_type(8)));
typedef _Float16 half4v __attribute__((ext_vector_type(4)));
typedef float    floatx4 __attribute__((ext_vector_type(4)));

// ---------------- pre-pass: fp32 -> f16 for x and W ----------------
__global__ __launch_bounds__(256)
void cvt_f16(const float* __restrict__ x, const float* __restrict__ W,
             _Float16* __restrict__ xh, _Float16* __restrict__ Wh) {
    int idx = blockIdx.x * 256 + threadIdx.x;
    const int stride = gridDim.x * 256;
    for (; idx < TOT_V4; idx += stride) {
        const float* src; _Float16* dst; int o;
        if (idx < X_V4) { src = x; dst = xh; o = idx * 4; }
        else            { src = W; dst = Wh; o = (idx - X_V4) * 4; }
        const floatx4 v = *(const floatx4*)(src + o);
        half4v h;
        h[0] = (_Float16)v[0]; h[1] = (_Float16)v[1];
        h[2] = (_Float16)v[2]; h[3] = (_Float16)v[3];
        *(half4v*)(dst + o) = h;
    }
}

// ---------------- main: f16 reads, LDS-transpose epilogue for full-line stores ----
__global__ __launch_bounds__(256, 4)
void bilinear_f16(const _Float16* __restrict__ xh, const _Float16* __restrict__ Wh,
                  float* __restrict__ out) {
    // Per-wave 32x64 f32 result staging (transpose so stores are line-contiguous)
    __shared__ float sOut[4 * 32 * LDSF];   // 34816 B

    const int tid  = threadIdx.x;
    const int lane = tid & 63;
    const int wv   = tid >> 6;      // wave id 0..3 -> rows [wv*32, wv*32+32)
    const int lrow = lane & 15;
    const int quad = lane >> 4;

    const int p  = blockIdx.x % NPAIRS;   // pair-inner: contiguous block chunks share one x batch tile
    const int bt = blockIdx.x / NPAIRS;
    const int b0 = bt * MTILE;

    // decode lexicographic combinations(range(32), 2): p -> (fi, fj)
    int fi = 0, rem = p;
    while (rem >= NF - 1 - fi) { rem -= NF - 1 - fi; ++fi; }
    const int fj = fi + 1 + rem;

    // ---- A-operand: W[p] fragments straight from global (f16, L2-hot) ----
    const _Float16* Wp = Wh + (size_t)p * (DIM * DIM);
    half8 aw[2][4];   // [ks][ot]
    #pragma unroll
    for (int ks = 0; ks < 2; ++ks)
        #pragma unroll
        for (int ot = 0; ot < 4; ++ot)
            aw[ks][ot] = *(const half8*)(Wp + (ot * 16 + lrow) * DIM + ks * 32 + quad * 8);

    // ---- B-operand: x_i fragments direct to registers (f16) ----
    half8 bx[2][2];   // [bt2][ks]
    #pragma unroll
    for (int bt2 = 0; bt2 < 2; ++bt2) {
        const int b = b0 + wv * 32 + bt2 * 16 + lrow;
        const _Float16* xrow = xh + ((size_t)b * NF + fi) * DIM;
        #pragma unroll
        for (int ks = 0; ks < 2; ++ks)
            bx[bt2][ks] = *(const half8*)(xrow + ks * 32 + quad * 8);
    }

    // ---- MFMA (swapped): D[o][b] = A(W) * B(x_i) ----
    // D layout: col = lane&15 -> batch sub-row (b = bt2*16+lrow),
    //           row = quad*4 + r -> o (4 consecutive o per lane)
    floatx4 acc[2][4] = {};   // [bt2][ot]
    #pragma unroll
    for (int ks = 0; ks < 2; ++ks)
        #pragma unroll
        for (int bt2 = 0; bt2 < 2; ++bt2)
            #pragma unroll
            for (int ot = 0; ot < 4; ++ot)
                acc[bt2][ot] = __builtin_amdgcn_mfma_f32_16x16x32_f16(aw[ks][ot], bx[bt2][ks], acc[bt2][ot], 0, 0, 0);

    // ---- stage result tile to per-wave LDS region ----
    float* swv = sOut + wv * (32 * LDSF);
    #pragma unroll
    for (int bt2 = 0; bt2 < 2; ++bt2)
        #pragma unroll
        for (int ot = 0; ot < 4; ++ot)
            *(floatx4*)(&swv[(bt2 * 16 + lrow) * LDSF + ot * 16 + quad * 4]) = acc[bt2][ot];

    __syncthreads();   // cross-lane LDS exchange: fence compiler + HW ordering

    // ---- transposed read-back: each store instr = 4 x 256B contiguous (full lines) ----
    const int rsub = lane >> 4;        // 0..3: which of the 4 rows this instr covers
    const int c4   = (lane & 15) * 4;  // 16 lanes x 4 floats = 256B contiguous row chunk
    #pragma unroll
    for (int k = 0; k < 8; ++k) {
        const int row = k * 4 + rsub;  // 0..31 within wave's tile
        const floatx4 v = *(const floatx4*)(&swv[row * LDSF + c4]);
        const size_t b = (size_t)(b0 + wv * 32 + row);
        const half4v xj = *(const half4v*)(xh + (b * NF + fj) * DIM + c4);
        floatx4 res;
        res[0] = v[0] * (float)xj[0]; res[1] = v[1] * (float)xj[1];
        res[2] = v[2] * (float)xj[2]; res[3] = v[3] * (float)xj[3];
        __builtin_nontemporal_store(res, (floatx4*)(out + b * (NPAIRS * DIM) + (size_t)p * DIM + c4));
    }
}

// ---------------- fallback (ws too small): Round-3 kernel, fp32 reads ----------------
#define LDAP 72
__global__ __launch_bounds__(256, 4)
void bilinear_fb(const float* __restrict__ x, const float* __restrict__ W,
                 float* __restrict__ out) {
    __shared__ _Float16 sW[DIM * LDAP];
    const int tid = threadIdx.x, lane = tid & 63, wv = tid >> 6;
    const int lrow = lane & 15, quad = lane >> 4;
    const int p = blockIdx.x % NPAIRS, bt = blockIdx.x / NPAIRS, b0 = bt * MTILE;
    int fi = 0, rem = p;
    while (rem >= NF - 1 - fi) { rem -= NF - 1 - fi; ++fi; }
    const int fj = fi + 1 + rem;
    const float* Wp = W + (size_t)p * (DIM * DIM);
    #pragma unroll
    for (int it = 0; it < 4; ++it) {
        int idx = tid + 256 * it, o = idx >> 4, c4 = (idx & 15) << 2;
        const floatx4 v = *(const floatx4*)(Wp + o * DIM + c4);
        half4v hv; hv[0]=(_Float16)v[0]; hv[1]=(_Float16)v[1]; hv[2]=(_Float16)v[2]; hv[3]=(_Float16)v[3];
        *(half4v*)(&sW[o * LDAP + c4]) = hv;
    }
    half8 bx[2][2];
    #pragma unroll
    for (int bt2 = 0; bt2 < 2; ++bt2) {
        const int b = b0 + wv * 32 + bt2 * 16 + lrow;
        const float* xrow = x + ((size_t)b * NF + fi) * DIM;
        #pragma unroll
        for (int ks = 0; ks < 2; ++ks) {
            const floatx4 v0 = *(const floatx4*)(xrow + ks * 32 + quad * 8);
            const floatx4 v1 = *(const floatx4*)(xrow + ks * 32 + quad * 8 + 4);
            half8 h;
            h[0]=(_Float16)v0[0]; h[1]=(_Float16)v0[1]; h[2]=(_Float16)v0[2]; h[3]=(_Float16)v0[3];
            h[4]=(_Float16)v1[0]; h[5]=(_Float16)v1[1]; h[6]=(_Float16)v1[2]; h[7]=(_Float16)v1[3];
            bx[bt2][ks] = h;
        }
    }
    __syncthreads();
    floatx4 acc[2][4] = {};
    #pragma unroll
    for (int ks = 0; ks < 2; ++ks) {
        half8 aw[4];
        #pragma unroll
        for (int ot = 0; ot < 4; ++ot)
            aw[ot] = *(const half8*)(&sW[(ot * 16 + lrow) * LDAP + ks * 32 + quad * 8]);
        #pragma unroll
        for (int bt2 = 0; bt2 < 2; ++bt2)
            #pragma unroll
            for (int ot = 0; ot < 4; ++ot)
                acc[bt2][ot] = __builtin_amdgcn_mfma_f32_16x16x32_f16(aw[ot], bx[bt2][ks], acc[bt2][ot], 0, 0, 0);
    }
    #pragma unroll
    for (int bt2 = 0; bt2 < 2; ++bt2) {
        const size_t b = (size_t)(b0 + wv * 32 + bt2 * 16 + lrow);
        const float* xjrow = x + (b * NF + fj) * DIM;
        float* orow = out + b * (NPAIRS * DIM) + (size_t)p * DIM;
        #pragma unroll
        for (int ot = 0; ot < 4; ++ot) {
            const int o4 = ot * 16 + quad * 4;
            const floatx4 xj = *(const floatx4*)(xjrow + o4);
            const floatx4 a = acc[bt2][ot];
            floatx4 res;
            res[0]=a[0]*xj[0]; res[1]=a[1]*xj[1]; res[2]=a[2]*xj[2]; res[3]=a[3]*xj[3];
            __builtin_nontemporal_store(res, (floatx4*)(orow + o4));
        }
    }
}

extern "C" void kernel_launch(void* const* d_in, const int* in_sizes, int n_in,
                              void* d_out, int out_size, void* d_ws, size_t ws_size,
                              hipStream_t stream) {
    const float* x = (const float*)d_in[0];   // (4096, 32, 64) fp32
    const float* W = (const float*)d_in[1];   // (496, 64, 64) fp32
    float* out = (float*)d_out;               // (4096, 496, 64) fp32

    const size_t need = (size_t)(X_ELEMS + W_ELEMS) * sizeof(_Float16);  // 20.9 MB
    dim3 grid(NPAIRS * (NBATCH / MTILE));     // 15872 blocks

    if (ws_size >= need) {
        _Float16* xh = (_Float16*)d_ws;
        _Float16* Wh = xh + X_ELEMS;
        cvt_f16<<<dim3(2048), 256, 0, stream>>>(x, W, xh, Wh);
        bilinear_f16<<<grid, 256, 0, stream>>>(xh, Wh, out);
    } else {
        bilinear_fb<<<grid, 256, 0, stream>>>(x, W, out);
    }
}